// Round 21
// baseline (81.404 us; speedup 1.0000x reference)
//
#include <hip/hip_runtime.h>
#include <hip/hip_bf16.h>

using bf16 = __hip_bfloat16;
typedef __attribute__((ext_vector_type(8))) short short8;
typedef __attribute__((ext_vector_type(4))) float f32x4;
typedef __attribute__((ext_vector_type(16))) float f32x16;

__device__ __constant__ int c_dil[8] = {1, 2, 4, 8, 1, 2, 4, 8};

__device__ inline void store1(float* p, float v) { *p = v; }
__device__ inline void store1(bf16* p, float v) { *p = __float2bfloat16(v); }

// async global->LDS, 16 B per lane; LDS dest wave-uniform base (+ lane*16 by HW)
__device__ inline void gload_lds16(const void* g, void* l) {
    __builtin_amdgcn_global_load_lds(
        (const __attribute__((address_space(1))) unsigned int*)g,
        (__attribute__((address_space(3))) unsigned int*)l, 16, 0, 0);
}

template <int N> __device__ inline void vwait() {
    asm volatile("s_waitcnt vmcnt(%0)" :: "n"(N) : "memory");
    __builtin_amdgcn_sched_barrier(0);
}
__device__ inline void barrier_pin() {
    __builtin_amdgcn_s_barrier();
    __builtin_amdgcn_sched_barrier(0);
}

// manual RNE f32->bf16
__device__ inline unsigned short f2bf(float f) {
    const unsigned u = __float_as_uint(f);
    return (unsigned short)((u + 0x7fffu + ((u >> 16) & 1u)) >> 16);
}
__device__ inline float bf2f(unsigned short h) { return __uint_as_float(((unsigned)h) << 16); }

// ---------------- fused convert: f32 -> bf16 (+ job-counter init) ----------------
// mode 0: row = ld, plain;  mode 1: row = 1024, [hi|lo] (x)
__device__ inline void conv_block(const float* __restrict__ src, bf16* __restrict__ dst,
                                  int ld, int mode, int idx) {
    const float4 v = *reinterpret_cast<const float4*>(src + idx);
    const int r = idx >> 9, c = idx & 511;
    bf16* d = dst + (size_t)r * ld + c;
    const float vv[4] = {v.x, v.y, v.z, v.w};
    ushort4 hi, lo;
    unsigned short* hp = &hi.x; unsigned short* lp = &lo.x;
#pragma unroll
    for (int j = 0; j < 4; ++j) {
        hp[j] = f2bf(vv[j]);
        lp[j] = f2bf(vv[j] - bf2f(hp[j]));
    }
    *reinterpret_cast<ushort4*>(d) = hi;
    if (mode == 1) *reinterpret_cast<ushort4*>(d + 512) = lo;
}

__global__ __launch_bounds__(256) void conv_all(
    const float* __restrict__ x,  const float* __restrict__ qw, const float* __restrict__ kw,
    const float* __restrict__ vw, const float* __restrict__ ow,
    const float* __restrict__ qb, const float* __restrict__ kb,
    bf16* A2, bf16* Wqk, bf16* Wv, bf16* Wo, float* bqk, int* counter)
{
    const int b = blockIdx.x, t = threadIdx.x;
    if (b < 2048)       conv_block(x,  A2,                      1024, 1, (b * 256 + t) * 4);
    else if (b < 2304)  conv_block(qw, Wqk,                      512, 0, ((b - 2048) * 256 + t) * 4);
    else if (b < 3584)  conv_block(kw, Wqk + (size_t)512 * 512,  512, 0, ((b - 2304) * 256 + t) * 4);
    else if (b < 4864)  conv_block(vw, Wv,                       512, 0, ((b - 3584) * 256 + t) * 4);
    else if (b < 5120)  conv_block(ow, Wo,                       512, 0, ((b - 4864) * 256 + t) * 4);
    else if (b < 5132) { const int i = (b - 5120) * 256 + t; bqk[i] = (i < 512) ? qb[i] : kb[i - 512]; }
    else if (t == 0)    *counter = 0;   // job counter for the persistent QKV kernel
}

// ======== QKV engine (r20-proven): BM=128, BN=256, BK=32, 4 waves, 32x32 MFMA ==========
// HILO=true: C = x_hi.w + x_lo.w (exact-x, 2x MFMA, B frags reused in regs).
// Fragment layout (r8/r20-validated): A/B row = lane&31, k = ksub*16 + (lane>>5)*8;
// C/D col=lane&31, row=(j&3)+8*(j>>2)+4*(lane>>5). One barrier per kt; WAR by parity.
// Swizzle: phys 16B slot = logical ^ ((row>>1)&3), pre-applied on the staging source.
template <bool HILO>
__device__ __forceinline__ void run_gemm(
    short* smem,
    const bf16* __restrict__ A,            // ld 1024 ([hi|lo]; plain reads hi only)
    const bf16* __restrict__ W,            // ld 512
    const float* __restrict__ bias,
    bf16* __restrict__ C, int ldc,
    int bm, int bn)
{
    constexpr int NSTEPS = 16;             // K = 512
    short* Ahi = smem;                     // 2 x 4096 shorts (8 KB)
    short* Alo = smem + 8192;              // 2 x 4096 (HILO only)
    short* Bs  = smem + 16384;             // 2 x 8192 (16 KB: [256][32])

    const int tid = threadIdx.x, wid = tid >> 6, lane = tid & 63;

    const int sslot = (((tid & 3) ^ ((tid >> 3) & 3)) << 4);   // swizzled 16B slot (bytes)
    const char* pAh = (const char*)A + (size_t)(bm + (tid >> 2)) * 2048 + sslot;
    const char* pB0 = (const char*)W + (size_t)(bn + (tid >> 2)) * 1024 + sslot;

    auto stage = [&](int kt) {
        char* da = (char*)(Ahi + (kt & 1) * 4096);
        char* db = (char*)(Bs  + (kt & 1) * 8192);
        gload_lds16(pAh,          da + wid * 1024);            // A rows 0-63
        gload_lds16(pAh + 131072, da + 4096 + wid * 1024);     // A rows 64-127
        if (HILO) {
            char* dl = (char*)(Alo + (kt & 1) * 4096);
            gload_lds16(pAh + 1024,          dl + wid * 1024);          // lo half (+512 cols)
            gload_lds16(pAh + 1024 + 131072, dl + 4096 + wid * 1024);
        }
        gload_lds16(pB0,           db + wid * 1024);           // B rows 0-63
        gload_lds16(pB0 + 65536,   db + 4096 + wid * 1024);    // B rows 64-127
        gload_lds16(pB0 + 131072,  db + 8192 + wid * 1024);    // B rows 128-191
        gload_lds16(pB0 + 196608,  db + 12288 + wid * 1024);   // B rows 192-255
        pAh += 64; pB0 += 64;
    };

    f32x16 acc[2][4];
#pragma unroll
    for (int m = 0; m < 2; ++m)
#pragma unroll
        for (int n = 0; n < 4; ++n)
#pragma unroll
            for (int j = 0; j < 16; ++j) acc[m][n][j] = 0.f;

    const int l31  = lane & 31;
    const int khalf = lane >> 5;                               // 0,1 -> k 0-7 / 8-15
    const int swz  = (l31 >> 1) & 3;
    const int k0   = ((khalf)     ^ swz) << 3;                 // ksub 0, shorts
    const int k1   = ((2 + khalf) ^ swz) << 3;                 // ksub 1
    const int wrM = wid >> 1, wcN = wid & 1;                   // 2x2 wave grid
    const int arow0 = wrM * 64 + l31;                          // + m*32
    const int brow0 = wcN * 128 + l31;                         // + n*32

    stage(0);

    for (int kt = 0; kt < NSTEPS; ++kt) {
        vwait<0>();          // my stage(kt) landed (one full read+MFMA phase of cover)
        barrier_pin();       // all waves' stage(kt) landed -> buf kt valid

        const short* ah = Ahi + (kt & 1) * 4096;
        const short* al = Alo + (kt & 1) * 4096;
        const short* bb = Bs  + (kt & 1) * 8192;
        short8 fh[2][2], fl[2][2], bw[2][4];
#pragma unroll
        for (int m = 0; m < 2; ++m) {
            fh[0][m] = *(const short8*)&ah[(arow0 + m * 32) * 32 + k0];
            fh[1][m] = *(const short8*)&ah[(arow0 + m * 32) * 32 + k1];
            if (HILO) {
                fl[0][m] = *(const short8*)&al[(arow0 + m * 32) * 32 + k0];
                fl[1][m] = *(const short8*)&al[(arow0 + m * 32) * 32 + k1];
            }
        }
#pragma unroll
        for (int n = 0; n < 4; ++n) {
            bw[0][n] = *(const short8*)&bb[(brow0 + n * 32) * 32 + k0];
            bw[1][n] = *(const short8*)&bb[(brow0 + n * 32) * 32 + k1];
        }

        if (kt + 1 < NSTEPS) stage(kt + 1);    // opposite buffer; readers long retired

        __builtin_amdgcn_s_setprio(1);
#pragma unroll
        for (int ks = 0; ks < 2; ++ks)
#pragma unroll
            for (int m = 0; m < 2; ++m)
#pragma unroll
                for (int n = 0; n < 4; ++n)
                    acc[m][n] = __builtin_amdgcn_mfma_f32_32x32x16_bf16(fh[ks][m], bw[ks][n], acc[m][n], 0, 0, 0);
        if (HILO) {
#pragma unroll
            for (int ks = 0; ks < 2; ++ks)
#pragma unroll
                for (int m = 0; m < 2; ++m)
#pragma unroll
                    for (int n = 0; n < 4; ++n)
                        acc[m][n] = __builtin_amdgcn_mfma_f32_32x32x16_bf16(fl[ks][m], bw[ks][n], acc[m][n], 0, 0, 0);
        }
        __builtin_amdgcn_s_setprio(0);
    }

    // epilogue: 32x32 C/D layout col=lane&31, row=(j&3)+8*(j>>2)+4*(lane>>5)
    const int rb4 = 4 * khalf;
#pragma unroll
    for (int m = 0; m < 2; ++m) {
#pragma unroll
        for (int n = 0; n < 4; ++n) {
            const int col = bn + wcN * 128 + n * 32 + l31;
            const float bv = bias[col];
#pragma unroll
            for (int j = 0; j < 16; ++j) {
                const int row = bm + wrM * 64 + m * 32 + (j & 3) + 8 * (j >> 2) + rb4;
                store1(C + (size_t)row * ldc + col, acc[m][n][j] + bv);
            }
        }
    }
}

// Persistent QKV: 512 blocks (2/CU, all co-resident) dynamically grab jobs 0..703.
// Jobs heavy-first: 0-63 Q (hilo), 64-383 K (plain, +512 offsets), 384-703 V (plain).
// Output-deterministic: jobs write disjoint tiles; grab order only affects timing.
__global__ __launch_bounds__(256, 2) void gemm_qkv(
    const bf16* __restrict__ A,
    const bf16* __restrict__ Wqk, const float* __restrict__ bqk, bf16* __restrict__ PQK,
    const bf16* __restrict__ Wv,  const float* __restrict__ vb,  bf16* __restrict__ PV,
    int* __restrict__ counter)
{
    __shared__ short smem[32768];   // 64 KB -> 2 blocks/CU
    __shared__ int s_job;

    for (;;) {
        __syncthreads();                       // prior job's LDS reads + s_job reads done
        if (threadIdx.x == 0) s_job = atomicAdd(counter, 1);
        __syncthreads();
        const int job = s_job;
        if (job >= 704) break;

        if (job < 64) {
            const int by = job >> 1, bx = job & 1;
            run_gemm<true>(smem, A, Wqk, bqk, PQK, 3072, by * 128, bx * 256);
        } else if (job < 384) {
            const int t = job - 64;
            const int by = t / 10, bx = t % 10;
            run_gemm<false>(smem, A, Wqk + (size_t)512 * 512, bqk + 512,
                            PQK + 512, 3072, by * 128, bx * 256);
        } else {
            const int t = job - 384;
            const int by = t / 10, bx = t % 10;
            run_gemm<false>(smem, A, Wv, vb, PV, 2560, by * 128, bx * 256);
        }
    }
}

// ---------------- O-projection GEMM, 128 x 64 tile, de-pinned (1 barrier/step) ---------
template <int BN, typename TC>
__global__ __launch_bounds__(256) void gemm128(
    const bf16* __restrict__ A, int lda, int cw, int rpx,
    const bf16* __restrict__ W0, int ldw0, const float* __restrict__ b0,
    TC* __restrict__ C0, int ldc0, int nt0, int nx0)
{
    constexpr int NF = BN / 32;
    constexpr int NLOAD = (BN == 128) ? 4 : 3;
    __shared__ short As[4][128 * 32];
    __shared__ short Bs[4][BN * 32];

    const int tid = threadIdx.x, wid = tid >> 6, lane = tid & 63;

    const int xcd = (int)blockIdx.x & 7;
    const int i   = (int)blockIdx.x >> 3;
    const int grp = rpx * cw;
    const int cc = i / grp, w2 = i % grp;
    const int rr = w2 / cw, c = w2 % cw;
    const int bx = cc * cw + c;
    const int by = xcd * rpx + rr;

    const int bm = by * 128;
    const int bn = bx * BN;
    const int nsteps = nt0;

    const int srow = lane >> 2;
    const int ssw  = (((lane & 3) ^ ((lane >> 3) & 3)) << 4);
    const char* pA0 = (const char*)A + (size_t)(bm + wid * 16 + srow) * lda * 2 + ssw;
    const char* pA1 = pA0 + (size_t)64 * lda * 2;
    const char* pB0 = (const char*)W0 + (size_t)(bn + wid * 16 + srow) * ldw0 * 2 + ssw;

    f32x4 acc[4][NF];
#pragma unroll
    for (int m = 0; m < 4; ++m)
#pragma unroll
        for (int n = 0; n < NF; ++n) acc[m][n] = f32x4{0.f, 0.f, 0.f, 0.f};

    const int lr16 = lane & 15;
    const int wsw8 = (((lane >> 4) ^ ((lr16 >> 1) & 3)) << 3);
    const int wr = wid >> 1, wc = wid & 1;
    int offA[4], offB[NF];
#pragma unroll
    for (int m = 0; m < 4; ++m) offA[m] = (wr * 4 + m) * 512 + lr16 * 32 + wsw8;
#pragma unroll
    for (int n = 0; n < NF; ++n) offB[n] = (wc * NF + n) * 512 + lr16 * 32 + wsw8;

    auto stage = [&](int buf) {
        gload_lds16(pA0, (char*)As[buf] + wid * 1024);
        gload_lds16(pA1, (char*)As[buf] + (wid + 4) * 1024);
        gload_lds16(pB0, (char*)Bs[buf] + wid * 1024);
        pA0 += 64; pA1 += 64; pB0 += 64;
    };

    stage(0);
    stage(1);
    stage(2);

    for (int s = 0; s < nsteps; ++s) {
        const int cur = s & 3;
        if (s + 2 < nsteps)      vwait<2 * NLOAD>();
        else if (s + 1 < nsteps) vwait<NLOAD>();
        else                     vwait<0>();
        barrier_pin();

        if (s + 3 < nsteps) stage((s + 3) & 3);

        short8 af[4], bw[NF];
#pragma unroll
        for (int m = 0; m < 4; ++m)
            af[m] = *(const short8*)&As[cur][offA[m]];
#pragma unroll
        for (int n = 0; n < NF; ++n)
            bw[n] = *(const short8*)&Bs[cur][offB[n]];

        __builtin_amdgcn_s_setprio(1);
#pragma unroll
        for (int m = 0; m < 4; ++m)
#pragma unroll
            for (int n = 0; n < NF; ++n)
                acc[m][n] = __builtin_amdgcn_mfma_f32_16x16x32_bf16(af[m], bw[n], acc[m][n], 0, 0, 0);
        __builtin_amdgcn_s_setprio(0);
    }

    const int r4 = (lane >> 4) * 4;
#pragma unroll
    for (int m = 0; m < 4; ++m) {
#pragma unroll
        for (int n = 0; n < NF; ++n) {
            const int col = bn + wc * (NF * 16) + n * 16 + lr16;
            const float bv = b0[col];
#pragma unroll
            for (int jj = 0; jj < 4; ++jj) {
                const int row = bm + wr * 64 + m * 16 + r4 + jj;
                store1(C0 + (size_t)row * ldc0 + col, acc[m][n][jj] + bv);
            }
        }
    }
}

// ---------------- local attention stitch, vectorized (wave per (b,l), 16 B/lane) -------
__global__ __launch_bounds__(256) void attn_k(
    const bf16* __restrict__ PQK, const bf16* __restrict__ PV, bf16* __restrict__ Aout)
{
    const int lane = threadIdx.x & 63;
    const int wave = threadIdx.x >> 6;
    const int bl = blockIdx.x * 4 + wave;     // 0..8191
    const int l  = bl & 2047;
    const int h  = lane >> 3;
    const int d  = c_dil[h];
    const int o8 = (lane & 7) * 8;

    float q[8];
    {
        const short8 qv = *(const short8*)&PQK[(size_t)bl * 3072 + lane * 8];
#pragma unroll
        for (int i = 0; i < 8; ++i) q[i] = bf2f((unsigned short)qv[i]);
    }

    float logits[5];
    float vv[5][8];
#pragma unroll
    for (int kk = 0; kk < 5; ++kk) {
        const int pos = l + (kk - 2) * d;
        const bool ok = (pos >= 0) && (pos < 2048);
        float s = 0.f;
        if (ok) {
            const size_t rb = (size_t)(bl - l + pos);
            const int coff = h * 320 + kk * 64 + o8;
            const short8 kv = *(const short8*)&PQK[rb * 3072 + 512 + coff];
            const short8 vvv = *(const short8*)&PV[rb * 2560 + coff];
#pragma unroll
            for (int i = 0; i < 8; ++i) {
                s = fmaf(bf2f((unsigned short)kv[i]), q[i], s);
                vv[kk][i] = bf2f((unsigned short)vvv[i]);
            }
        } else {
#pragma unroll
            for (int i = 0; i < 8; ++i) vv[kk][i] = 0.f;
        }
        s += __shfl_xor(s, 1);
        s += __shfl_xor(s, 2);
        s += __shfl_xor(s, 4);
        logits[kk] = s;
    }

    float mx = logits[0];
#pragma unroll
    for (int kk = 1; kk < 5; ++kk) mx = fmaxf(mx, logits[kk]);
    float e[5], ssum = 0.f;
#pragma unroll
    for (int kk = 0; kk < 5; ++kk) { e[kk] = __expf(logits[kk] - mx); ssum += e[kk]; }
    const float sc = 0.125f / ssum;

    short8 outv;
#pragma unroll
    for (int i = 0; i < 8; ++i) {
        float a = 0.f;
#pragma unroll
        for (int kk = 0; kk < 5; ++kk) a = fmaf(e[kk], vv[kk][i], a);
        outv[i] = (short)f2bf(a * sc);
    }
    *(short8*)&Aout[(size_t)bl * 512 + lane * 8] = outv;
}

// ---------------- launch ----------------
extern "C" void kernel_launch(void* const* d_in, const int* in_sizes, int n_in,
                              void* d_out, int out_size, void* d_ws, size_t ws_size,
                              hipStream_t stream)
{
    const float* x   = (const float*)d_in[0];
    const float* q_w = (const float*)d_in[1];
    const float* q_b = (const float*)d_in[2];
    const float* k_w = (const float*)d_in[3];
    const float* k_b = (const float*)d_in[4];
    const float* v_w = (const float*)d_in[5];
    const float* v_b = (const float*)d_in[6];
    const float* o_w = (const float*)d_in[7];
    const float* o_b = (const float*)d_in[8];
    float* out = (float*)d_out;

    const int M = 4096;

    // workspace: A2 8 + Wqk 3 + Wv 2.5 + Wo 0.5 + bqk 0.012 + PQK 24 + PV 20 + ctr = 58 MB
    char* p = (char*)d_ws;
    bf16* A2  = (bf16*)p;  p += (size_t)M * 1024 * 2;       // [x_hi | x_lo]
    bf16* Wqk = (bf16*)p;  p += (size_t)3072 * 512 * 2;     // q rows 0-511, k rows 512-3071
    bf16* Wv  = (bf16*)p;  p += (size_t)2560 * 512 * 2;
    bf16* Wo  = (bf16*)p;  p += (size_t)512 * 512 * 2;
    float* bqk = (float*)p; p += 3072 * 4;
    bf16* PQK = (bf16*)p;  p += (size_t)M * 3072 * 2;
    bf16* PV  = (bf16*)p;  p += (size_t)M * 2560 * 2;
    int* counter = (int*)p;
    bf16* Aout = A2;  // A2 dead after the QKV GEMM; reuse for attention output

    conv_all<<<dim3(5133), dim3(256), 0, stream>>>(x, q_w, k_w, v_w, o_w, q_b, k_b,
                                                   A2, Wqk, Wv, Wo, bqk, counter);
    // 512 persistent blocks (2/CU) work-steal 704 jobs: 64 Q (hilo) + 320 K + 320 V
    gemm_qkv<<<dim3(512), dim3(256), 0, stream>>>(A2, Wqk, bqk, PQK, Wv, v_b, PV, counter);
    attn_k<<<dim3(2048), dim3(256), 0, stream>>>(PQK, PV, Aout);
    // grid 256 = 8 XCD x (4 rows x 8 cols)
    gemm128<64, float><<<dim3(256), dim3(256), 0, stream>>>(
        Aout, 512, /*cw*/8, /*rpx*/4,
        Wo, 512, o_b, out, 512, 16, 8);
}

// Round 22
// 71.622 us; speedup vs baseline: 1.1366x; 1.1366x over previous
//
#include <hip/hip_runtime.h>
#include <hip/hip_bf16.h>

using bf16 = __hip_bfloat16;
typedef __attribute__((ext_vector_type(8))) short short8;
typedef __attribute__((ext_vector_type(4))) float f32x4;
typedef __attribute__((ext_vector_type(16))) float f32x16;

__device__ __constant__ int c_dil[8] = {1, 2, 4, 8, 1, 2, 4, 8};

__device__ inline void store1(float* p, float v) { *p = v; }
__device__ inline void store1(bf16* p, float v) { *p = __float2bfloat16(v); }

// async global->LDS, 16 B per lane; LDS dest wave-uniform base (+ lane*16 by HW)
__device__ inline void gload_lds16(const void* g, void* l) {
    __builtin_amdgcn_global_load_lds(
        (const __attribute__((address_space(1))) unsigned int*)g,
        (__attribute__((address_space(3))) unsigned int*)l, 16, 0, 0);
}

template <int N> __device__ inline void vwait() {
    asm volatile("s_waitcnt vmcnt(%0)" :: "n"(N) : "memory");
    __builtin_amdgcn_sched_barrier(0);
}
__device__ inline void barrier_pin() {
    __builtin_amdgcn_s_barrier();
    __builtin_amdgcn_sched_barrier(0);
}

// manual RNE f32->bf16
__device__ inline unsigned short f2bf(float f) {
    const unsigned u = __float_as_uint(f);
    return (unsigned short)((u + 0x7fffu + ((u >> 16) & 1u)) >> 16);
}
__device__ inline float bf2f(unsigned short h) { return __uint_as_float(((unsigned)h) << 16); }

// ---------------- fused convert: f32 -> bf16 ----------------
// mode 0: row = ld, plain;  mode 1: row = 1024, [hi|lo] (x)
__device__ inline void conv_block(const float* __restrict__ src, bf16* __restrict__ dst,
                                  int ld, int mode, int idx) {
    const float4 v = *reinterpret_cast<const float4*>(src + idx);
    const int r = idx >> 9, c = idx & 511;
    bf16* d = dst + (size_t)r * ld + c;
    const float vv[4] = {v.x, v.y, v.z, v.w};
    ushort4 hi, lo;
    unsigned short* hp = &hi.x; unsigned short* lp = &lo.x;
#pragma unroll
    for (int j = 0; j < 4; ++j) {
        hp[j] = f2bf(vv[j]);
        lp[j] = f2bf(vv[j] - bf2f(hp[j]));
    }
    *reinterpret_cast<ushort4*>(d) = hi;
    if (mode == 1) *reinterpret_cast<ushort4*>(d + 512) = lo;
}

__global__ __launch_bounds__(256) void conv_all(
    const float* __restrict__ x,  const float* __restrict__ qw, const float* __restrict__ kw,
    const float* __restrict__ vw, const float* __restrict__ ow,
    const float* __restrict__ qb, const float* __restrict__ kb,
    bf16* A2, bf16* Wqk, bf16* Wv, bf16* Wo, float* bqk)
{
    const int b = blockIdx.x, t = threadIdx.x;
    if (b < 2048)       conv_block(x,  A2,                      1024, 1, (b * 256 + t) * 4);
    else if (b < 2304)  conv_block(qw, Wqk,                      512, 0, ((b - 2048) * 256 + t) * 4);
    else if (b < 3584)  conv_block(kw, Wqk + (size_t)512 * 512,  512, 0, ((b - 2304) * 256 + t) * 4);
    else if (b < 4864)  conv_block(vw, Wv,                       512, 0, ((b - 3584) * 256 + t) * 4);
    else if (b < 5120)  conv_block(ow, Wo,                       512, 0, ((b - 4864) * 256 + t) * 4);
    else { const int i = (b - 5120) * 256 + t; bqk[i] = (i < 512) ? qb[i] : kb[i - 512]; }
}

// ======== QKV engine r20: BM=128, BN=256, BK=32, 4 waves, wave-tile 64x128 =============
// Same staging/schedule as r17/r19 (proven); fragments use mfma_32x32x16_bf16:
// identical LDS bytes but half the MFMA instructions at the higher 32x32 rate.
// Fragment layout (r8-validated): A/B row = lane&31, k = ksub*16 + (lane>>5)*8; C/D
// col=lane&31, row=(j&3)+8*(j>>2)+4*(lane>>5). Swizzle: phys 16B slot = logical ^
// ((row>>1)&3), pre-applied on the global staging source, XORed on read offsets.
template <bool HILO>
__device__ __forceinline__ void run_gemm(
    short* smem,
    const bf16* __restrict__ A,            // ld 1024 ([hi|lo]; plain reads hi only)
    const bf16* __restrict__ W,            // ld 512
    const float* __restrict__ bias,
    bf16* __restrict__ C, int ldc,
    int bm, int bn)
{
    constexpr int NSTEPS = 16;             // K = 512
    short* Ahi = smem;                     // 2 x 4096 shorts (8 KB)
    short* Alo = smem + 8192;              // 2 x 4096 (HILO only)
    short* Bs  = smem + 16384;             // 2 x 8192 (16 KB: [256][32])

    const int tid = threadIdx.x, wid = tid >> 6, lane = tid & 63;

    const int sslot = (((tid & 3) ^ ((tid >> 3) & 3)) << 4);   // swizzled 16B slot (bytes)
    const char* pAh = (const char*)A + (size_t)(bm + (tid >> 2)) * 2048 + sslot;
    const char* pB0 = (const char*)W + (size_t)(bn + (tid >> 2)) * 1024 + sslot;

    auto stage = [&](int kt) {
        char* da = (char*)(Ahi + (kt & 1) * 4096);
        char* db = (char*)(Bs  + (kt & 1) * 8192);
        gload_lds16(pAh,          da + wid * 1024);            // A rows 0-63
        gload_lds16(pAh + 131072, da + 4096 + wid * 1024);     // A rows 64-127
        if (HILO) {
            char* dl = (char*)(Alo + (kt & 1) * 4096);
            gload_lds16(pAh + 1024,          dl + wid * 1024);          // lo half (+512 cols)
            gload_lds16(pAh + 1024 + 131072, dl + 4096 + wid * 1024);
        }
        gload_lds16(pB0,           db + wid * 1024);           // B rows 0-63
        gload_lds16(pB0 + 65536,   db + 4096 + wid * 1024);    // B rows 64-127
        gload_lds16(pB0 + 131072,  db + 8192 + wid * 1024);    // B rows 128-191
        gload_lds16(pB0 + 196608,  db + 12288 + wid * 1024);   // B rows 192-255
        pAh += 64; pB0 += 64;
    };

    f32x16 acc[2][4];
#pragma unroll
    for (int m = 0; m < 2; ++m)
#pragma unroll
        for (int n = 0; n < 4; ++n)
#pragma unroll
            for (int j = 0; j < 16; ++j) acc[m][n][j] = 0.f;

    const int l31  = lane & 31;
    const int khalf = lane >> 5;                               // 0,1 -> k 0-7 / 8-15
    const int swz  = (l31 >> 1) & 3;
    const int k0   = ((khalf)     ^ swz) << 3;                 // ksub 0, shorts
    const int k1   = ((2 + khalf) ^ swz) << 3;                 // ksub 1
    const int wrM = wid >> 1, wcN = wid & 1;                   // 2x2 wave grid
    const int arow0 = wrM * 64 + l31;                          // + m*32
    const int brow0 = wcN * 128 + l31;                         // + n*32

    stage(0);

    for (int kt = 0; kt < NSTEPS; ++kt) {
        vwait<0>();          // my stage(kt) landed (one full read+MFMA phase of cover)
        barrier_pin();       // all waves' stage(kt) landed -> buf kt valid

        const short* ah = Ahi + (kt & 1) * 4096;
        const short* al = Alo + (kt & 1) * 4096;
        const short* bb = Bs  + (kt & 1) * 8192;
        short8 fh[2][2], fl[2][2], bw[2][4];
#pragma unroll
        for (int m = 0; m < 2; ++m) {
            fh[0][m] = *(const short8*)&ah[(arow0 + m * 32) * 32 + k0];
            fh[1][m] = *(const short8*)&ah[(arow0 + m * 32) * 32 + k1];
            if (HILO) {
                fl[0][m] = *(const short8*)&al[(arow0 + m * 32) * 32 + k0];
                fl[1][m] = *(const short8*)&al[(arow0 + m * 32) * 32 + k1];
            }
        }
#pragma unroll
        for (int n = 0; n < 4; ++n) {
            bw[0][n] = *(const short8*)&bb[(brow0 + n * 32) * 32 + k0];
            bw[1][n] = *(const short8*)&bb[(brow0 + n * 32) * 32 + k1];
        }

        if (kt + 1 < NSTEPS) stage(kt + 1);    // opposite buffer; readers long retired

        __builtin_amdgcn_s_setprio(1);
#pragma unroll
        for (int ks = 0; ks < 2; ++ks)
#pragma unroll
            for (int m = 0; m < 2; ++m)
#pragma unroll
                for (int n = 0; n < 4; ++n)
                    acc[m][n] = __builtin_amdgcn_mfma_f32_32x32x16_bf16(fh[ks][m], bw[ks][n], acc[m][n], 0, 0, 0);
        if (HILO) {
#pragma unroll
            for (int ks = 0; ks < 2; ++ks)
#pragma unroll
                for (int m = 0; m < 2; ++m)
#pragma unroll
                    for (int n = 0; n < 4; ++n)
                        acc[m][n] = __builtin_amdgcn_mfma_f32_32x32x16_bf16(fl[ks][m], bw[ks][n], acc[m][n], 0, 0, 0);
        }
        __builtin_amdgcn_s_setprio(0);
    }

    // epilogue: 32x32 C/D layout col=lane&31, row=(j&3)+8*(j>>2)+4*(lane>>5)
    const int rb4 = 4 * khalf;
#pragma unroll
    for (int m = 0; m < 2; ++m) {
#pragma unroll
        for (int n = 0; n < 4; ++n) {
            const int col = bn + wcN * 128 + n * 32 + l31;
            const float bv = bias[col];
#pragma unroll
            for (int j = 0; j < 16; ++j) {
                const int row = bm + wrM * 64 + m * 32 + (j & 3) + 8 * (j >> 2) + rb4;
                store1(C + (size_t)row * ldc + col, acc[m][n][j] + bv);
            }
        }
    }
}

// Grid 704 (dispatch order = heavy first):
//   b <  64 : Q  blocks, HILO  (N=512), exact-x
//   b < 384 : K  blocks, plain (N=2560), W/bias/C offset +512
//   b < 704 : V  blocks, plain (N=2560) -> PV
__global__ __launch_bounds__(256, 2) void gemm_qkv(
    const bf16* __restrict__ A,
    const bf16* __restrict__ Wqk, const float* __restrict__ bqk, bf16* __restrict__ PQK,
    const bf16* __restrict__ Wv,  const float* __restrict__ vb,  bf16* __restrict__ PV)
{
    __shared__ short smem[32768];   // 64 KB -> 2 blocks/CU
    const int b = blockIdx.x;
    if (b < 64) {
        const int xcd = b & 7, i = b >> 3;           // 8/XCD: 4 rows x 2 cols
        const int by = xcd * 4 + (i & 3), bx = i >> 2;
        run_gemm<true>(smem, A, Wqk, bqk, PQK, 3072, by * 128, bx * 256);
    } else if (b < 384) {
        const int v = b - 64;
        const int xcd = v & 7, i = v >> 3;           // 40/XCD: 4 rows x 10 cols
        const int by = xcd * 4 + (i & 3), bx = i >> 2;
        run_gemm<false>(smem, A, Wqk + (size_t)512 * 512, bqk + 512,
                        PQK + 512, 3072, by * 128, bx * 256);
    } else {
        const int v = b - 384;
        const int xcd = v & 7, i = v >> 3;           // 40/XCD: 4 rows x 10 cols
        const int by = xcd * 4 + (i & 3), bx = i >> 2;
        run_gemm<false>(smem, A, Wv, vb, PV, 2560, by * 128, bx * 256);
    }
}

// ---------------- O-projection GEMM, 128 x 64 tile, de-pinned (1 barrier/step) ---------
template <int BN, typename TC>
__global__ __launch_bounds__(256) void gemm128(
    const bf16* __restrict__ A, int lda, int cw, int rpx,
    const bf16* __restrict__ W0, int ldw0, const float* __restrict__ b0,
    TC* __restrict__ C0, int ldc0, int nt0, int nx0)
{
    constexpr int NF = BN / 32;
    constexpr int NLOAD = (BN == 128) ? 4 : 3;
    __shared__ short As[4][128 * 32];
    __shared__ short Bs[4][BN * 32];

    const int tid = threadIdx.x, wid = tid >> 6, lane = tid & 63;

    const int xcd = (int)blockIdx.x & 7;
    const int i   = (int)blockIdx.x >> 3;
    const int grp = rpx * cw;
    const int cc = i / grp, w2 = i % grp;
    const int rr = w2 / cw, c = w2 % cw;
    const int bx = cc * cw + c;
    const int by = xcd * rpx + rr;

    const int bm = by * 128;
    const int bn = bx * BN;
    const int nsteps = nt0;

    const int srow = lane >> 2;
    const int ssw  = (((lane & 3) ^ ((lane >> 3) & 3)) << 4);
    const char* pA0 = (const char*)A + (size_t)(bm + wid * 16 + srow) * lda * 2 + ssw;
    const char* pA1 = pA0 + (size_t)64 * lda * 2;
    const char* pB0 = (const char*)W0 + (size_t)(bn + wid * 16 + srow) * ldw0 * 2 + ssw;

    f32x4 acc[4][NF];
#pragma unroll
    for (int m = 0; m < 4; ++m)
#pragma unroll
        for (int n = 0; n < NF; ++n) acc[m][n] = f32x4{0.f, 0.f, 0.f, 0.f};

    const int lr16 = lane & 15;
    const int wsw8 = (((lane >> 4) ^ ((lr16 >> 1) & 3)) << 3);
    const int wr = wid >> 1, wc = wid & 1;
    int offA[4], offB[NF];
#pragma unroll
    for (int m = 0; m < 4; ++m) offA[m] = (wr * 4 + m) * 512 + lr16 * 32 + wsw8;
#pragma unroll
    for (int n = 0; n < NF; ++n) offB[n] = (wc * NF + n) * 512 + lr16 * 32 + wsw8;

    auto stage = [&](int buf) {
        gload_lds16(pA0, (char*)As[buf] + wid * 1024);
        gload_lds16(pA1, (char*)As[buf] + (wid + 4) * 1024);
        gload_lds16(pB0, (char*)Bs[buf] + wid * 1024);
        pA0 += 64; pA1 += 64; pB0 += 64;
    };

    stage(0);
    stage(1);
    stage(2);

    for (int s = 0; s < nsteps; ++s) {
        const int cur = s & 3;
        if (s + 2 < nsteps)      vwait<2 * NLOAD>();
        else if (s + 1 < nsteps) vwait<NLOAD>();
        else                     vwait<0>();
        barrier_pin();

        if (s + 3 < nsteps) stage((s + 3) & 3);

        short8 af[4], bw[NF];
#pragma unroll
        for (int m = 0; m < 4; ++m)
            af[m] = *(const short8*)&As[cur][offA[m]];
#pragma unroll
        for (int n = 0; n < NF; ++n)
            bw[n] = *(const short8*)&Bs[cur][offB[n]];

        __builtin_amdgcn_s_setprio(1);
#pragma unroll
        for (int m = 0; m < 4; ++m)
#pragma unroll
            for (int n = 0; n < NF; ++n)
                acc[m][n] = __builtin_amdgcn_mfma_f32_16x16x32_bf16(af[m], bw[n], acc[m][n], 0, 0, 0);
        __builtin_amdgcn_s_setprio(0);
    }

    const int r4 = (lane >> 4) * 4;
#pragma unroll
    for (int m = 0; m < 4; ++m) {
#pragma unroll
        for (int n = 0; n < NF; ++n) {
            const int col = bn + wc * (NF * 16) + n * 16 + lr16;
            const float bv = b0[col];
#pragma unroll
            for (int jj = 0; jj < 4; ++jj) {
                const int row = bm + wr * 64 + m * 16 + r4 + jj;
                store1(C0 + (size_t)row * ldc0 + col, acc[m][n][jj] + bv);
            }
        }
    }
}

// ---------------- local attention stitch, vectorized (wave per (b,l), 16 B/lane) -------
__global__ __launch_bounds__(256) void attn_k(
    const bf16* __restrict__ PQK, const bf16* __restrict__ PV, bf16* __restrict__ Aout)
{
    const int lane = threadIdx.x & 63;
    const int wave = threadIdx.x >> 6;
    const int bl = blockIdx.x * 4 + wave;     // 0..8191
    const int l  = bl & 2047;
    const int h  = lane >> 3;
    const int d  = c_dil[h];
    const int o8 = (lane & 7) * 8;

    float q[8];
    {
        const short8 qv = *(const short8*)&PQK[(size_t)bl * 3072 + lane * 8];
#pragma unroll
        for (int i = 0; i < 8; ++i) q[i] = bf2f((unsigned short)qv[i]);
    }

    float logits[5];
    float vv[5][8];
#pragma unroll
    for (int kk = 0; kk < 5; ++kk) {
        const int pos = l + (kk - 2) * d;
        const bool ok = (pos >= 0) && (pos < 2048);
        float s = 0.f;
        if (ok) {
            const size_t rb = (size_t)(bl - l + pos);
            const int coff = h * 320 + kk * 64 + o8;
            const short8 kv = *(const short8*)&PQK[rb * 3072 + 512 + coff];
            const short8 vvv = *(const short8*)&PV[rb * 2560 + coff];
#pragma unroll
            for (int i = 0; i < 8; ++i) {
                s = fmaf(bf2f((unsigned short)kv[i]), q[i], s);
                vv[kk][i] = bf2f((unsigned short)vvv[i]);
            }
        } else {
#pragma unroll
            for (int i = 0; i < 8; ++i) vv[kk][i] = 0.f;
        }
        s += __shfl_xor(s, 1);
        s += __shfl_xor(s, 2);
        s += __shfl_xor(s, 4);
        logits[kk] = s;
    }

    float mx = logits[0];
#pragma unroll
    for (int kk = 1; kk < 5; ++kk) mx = fmaxf(mx, logits[kk]);
    float e[5], ssum = 0.f;
#pragma unroll
    for (int kk = 0; kk < 5; ++kk) { e[kk] = __expf(logits[kk] - mx); ssum += e[kk]; }
    const float sc = 0.125f / ssum;

    short8 outv;
#pragma unroll
    for (int i = 0; i < 8; ++i) {
        float a = 0.f;
#pragma unroll
        for (int kk = 0; kk < 5; ++kk) a = fmaf(e[kk], vv[kk][i], a);
        outv[i] = (short)f2bf(a * sc);
    }
    *(short8*)&Aout[(size_t)bl * 512 + lane * 8] = outv;
}

// ---------------- launch ----------------
extern "C" void kernel_launch(void* const* d_in, const int* in_sizes, int n_in,
                              void* d_out, int out_size, void* d_ws, size_t ws_size,
                              hipStream_t stream)
{
    const float* x   = (const float*)d_in[0];
    const float* q_w = (const float*)d_in[1];
    const float* q_b = (const float*)d_in[2];
    const float* k_w = (const float*)d_in[3];
    const float* k_b = (const float*)d_in[4];
    const float* v_w = (const float*)d_in[5];
    const float* v_b = (const float*)d_in[6];
    const float* o_w = (const float*)d_in[7];
    const float* o_b = (const float*)d_in[8];
    float* out = (float*)d_out;

    const int M = 4096;

    // workspace: A2 8 + Wqk 3 + Wv 2.5 + Wo 0.5 + bqk 0.012 + PQK 24 + PV 20 = 58 MB
    char* p = (char*)d_ws;
    bf16* A2  = (bf16*)p;  p += (size_t)M * 1024 * 2;       // [x_hi | x_lo]
    bf16* Wqk = (bf16*)p;  p += (size_t)3072 * 512 * 2;     // q rows 0-511, k rows 512-3071
    bf16* Wv  = (bf16*)p;  p += (size_t)2560 * 512 * 2;
    bf16* Wo  = (bf16*)p;  p += (size_t)512 * 512 * 2;
    float* bqk = (float*)p; p += 3072 * 4;
    bf16* PQK = (bf16*)p;  p += (size_t)M * 3072 * 2;
    bf16* PV  = (bf16*)p;
    bf16* Aout = A2;  // A2 dead after the QKV GEMM; reuse for attention output

    conv_all<<<dim3(5132), dim3(256), 0, stream>>>(x, q_w, k_w, v_w, o_w, q_b, k_b,
                                                   A2, Wqk, Wv, Wo, bqk);
    // 704 jobs: 64 Q (hilo, heavy, first) + 320 K (plain) + 320 V (plain)
    gemm_qkv<<<dim3(704), dim3(256), 0, stream>>>(A2, Wqk, bqk, PQK, Wv, v_b, PV);
    attn_k<<<dim3(2048), dim3(256), 0, stream>>>(PQK, PV, Aout);
    // grid 256 = 8 XCD x (4 rows x 8 cols)
    gemm128<64, float><<<dim3(256), dim3(256), 0, stream>>>(
        Aout, 512, /*cw*/8, /*rpx*/4,
        Wo, 512, o_b, out, 512, 16, 8);
}